// Round 13
// baseline (93.205 us; speedup 1.0000x reference)
//
#include <hip/hip_runtime.h>
#include <hip/hip_bf16.h>

// NT-Xent loss: B=4096, D=128, TEMP=0.5, N2=8192.
// loss = mean_i [ log sum_{j!=i} exp(2*sim_ij) - 2*pos_i ]
// sim = zn zn^T (bf16 MFMA), pos_i = fp32 cosine(z_i, z_{i^B}).
// Self-diagonal handled by rowsum init = -exp2(sii_scaled).
//
// R13: DECOUPLE WAVES. R12 halved MFMA/exp/LDS work -> total unchanged
// => sim is not throughput-bound; every pipe idles. Invariant suspect:
// per-round __syncthreads chains each block's 4 waves (on 4 different
// SIMDs) into convoys -> effective TLP ~1 wave/SIMD. This kernel has
// ZERO barriers: each wave owns 64 rows x 256 cols with a PRIVATE 2x4KB
// LDS double buffer, staged via global_load_lds (wave-uniform dest ✓)
// and drained by per-wave s_waitcnt vmcnt(0). Waves are fully
// independent streams. Cost: B not shared across waves (4x L2 B-traffic,
// ~268MB ~ 7us aggregate) — the experiment isolates convoy-coupling.
// Same XOR swizzle (q-parity folded into two pre-swizzled src pointers),
// same A-frag layout + liveness pin, same norm/finalize kernels.

#define BB 4096
#define N2 8192
#define DD 128
#define CSPLIT 32          // column splits (grid.x)
#define CW (N2 / CSPLIT)   // 256 cols per block/wave
#define NCT (CW / 16)      // 16 col-tile rounds per wave

// sqrt(2*log2(e)): zn scaled by this => A.B = 2*log2(e)*sim, so
// exp(2*sim) = exp2(A.B) directly.
#define SCALE 1.69864360f

#if __has_builtin(__builtin_amdgcn_exp2f)
#define EXP2F(x) __builtin_amdgcn_exp2f(x)
#else
#define EXP2F(x) __expf((x) * 0.6931471805599453f)
#endif

using bf16 = __hip_bfloat16;
typedef __attribute__((ext_vector_type(8))) short short8;   // MFMA A/B frag
typedef __attribute__((ext_vector_type(4))) float float4v;  // MFMA C/D frag

// async 16B global->LDS (gfx950: global_load_lds_dwordx4).
// LDS dest must be wave-uniform; HW writes dest + lane*16; src per-lane.
__device__ __forceinline__ void gl_lds16(const char* g, char* ldst) {
  __builtin_amdgcn_global_load_lds(
      (const __attribute__((address_space(1))) void*)g,
      (__attribute__((address_space(3))) void*)ldst, 16, 0, 0);
}

// ---------------- Kernel 1: per-pair normalize, scale, cast bf16 ----------
__global__ __launch_bounds__(256) void ntx_norm_kernel(
    const float* __restrict__ zi, const float* __restrict__ zj,
    bf16* __restrict__ zn, float* __restrict__ rowsum, float* __restrict__ pos) {
  const int wave = threadIdx.x >> 6;
  const int lane = threadIdx.x & 63;
  const int pair = blockIdx.x * 4 + wave;   // 1024 blocks, 4 pairs/block
  float2 v = ((const float2*)(zi + (size_t)pair * DD))[lane];
  float2 w = ((const float2*)(zj + (size_t)pair * DD))[lane];
  float s1 = v.x * v.x + v.y * v.y;
  float s2 = w.x * w.x + w.y * w.y;
  float s3 = v.x * w.x + v.y * w.y;
  #pragma unroll
  for (int o = 32; o > 0; o >>= 1) {
    s1 += __shfl_xor(s1, o);
    s2 += __shfl_xor(s2, o);
    s3 += __shfl_xor(s3, o);
  }
  float nv = fmaxf(sqrtf(s1), 1e-8f);
  float nw = fmaxf(sqrtf(s2), 1e-8f);
  float rv = SCALE / nv, rw = SCALE / nw;   // scale folded into zn
  bf16 bx = __float2bfloat16(v.x * rv);
  bf16 by = __float2bfloat16(v.y * rv);
  bf16 cx = __float2bfloat16(w.x * rw);
  bf16 cy = __float2bfloat16(w.y * rw);
  __hip_bfloat162 h2; h2.x = bx; h2.y = by;
  __hip_bfloat162 g2; g2.x = cx; g2.y = cy;
  ((__hip_bfloat162*)(zn + (size_t)pair * DD))[lane] = h2;
  ((__hip_bfloat162*)(zn + (size_t)(pair + BB) * DD))[lane] = g2;
  // self-dot in the SAME scaled bf16 precision the MFMA will see
  float fx = __bfloat162float(bx), fy = __bfloat162float(by);
  float gx = __bfloat162float(cx), gy = __bfloat162float(cy);
  float sii = fx * fx + fy * fy;            // = 2log2e * sim_ii (scaled)
  float sjj = gx * gx + gy * gy;
  #pragma unroll
  for (int o = 32; o > 0; o >>= 1) {
    sii += __shfl_xor(sii, o);
    sjj += __shfl_xor(sjj, o);
  }
  if (lane == 0) {
    float c = s3 / (nv * nw);               // fp32 positive-pair cosine
    rowsum[pair]      = -EXP2F(sii);        // cancels diagonal term
    rowsum[pair + BB] = -EXP2F(sjj);
    pos[pair]      = c;
    pos[pair + BB] = c;
  }
}

// ---------------- Kernel 2: fused sim + sum-exp (barrier-free) -------------
// grid (32, 32) = 1024 blocks, 4 waves each. Wave owns 64 rows x 256 cols,
// fully independent: private 2x4KB LDS double buffer, global_load_lds
// staging (1 col-tile = 16 cols = 4KB per round), per-wave vmcnt drain,
// NO __syncthreads anywhere.
__global__ __launch_bounds__(256) void ntx_sim_kernel(
    const bf16* __restrict__ zn, float* __restrict__ rowsum) {
  const int tid  = threadIdx.x;
  const int wave = tid >> 6;
  const int lane = tid & 63;
  const int quad = lane >> 4;
  const int l15  = lane & 15;
  const char* zb  = (const char*)zn;
  const short* zs = (const short*)zn;

  __shared__ float4 lds[2048];   // 32 KB = 4 waves x 2 bufs x 4 KB

  const int rowBase = blockIdx.y * 256 + wave * 64;
  const int colBase = blockIdx.x * CW;

  // Staging map per round (16 cols -> 4KB buffer, 256 chunks of 16B):
  // chunk p = q*64 + lane (q = 0..3, 4 gl_lds calls):
  //   LDS row g = p>>4 = 4q + (lane>>4), slot = p&15 = lane&15.
  //   Stored content = global chunk (slot ^ (g&7)) of col-row g, where
  //   g&7 = 4(q&1) + (lane>>4) -> two pre-swizzled src pointers (q parity).
  // -> swizzled ds_read_b128 reads are uniform across banks (verified R5+).
  const int gr = lane >> 4;    // row-within-4
  const int sl = lane & 15;
  const char* spE = zb + (size_t)(colBase + gr) * 256 + ((sl ^ gr) << 4);
  const char* spO = zb + (size_t)(colBase + gr) * 256 + ((sl ^ (4 + gr)) << 4);
  // q's col offset: 4q rows = q*1024 bytes (q even -> spE, q odd -> spO)

  char* wb = (char*)lds + wave * 8192;   // wave-private 8 KB

  // prologue: stage round 0 into buf0 (async)
  gl_lds16(spE,        wb);
  gl_lds16(spO + 1024, wb + 1024);
  gl_lds16(spE + 2048, wb + 2048);
  gl_lds16(spO + 3072, wb + 3072);

  // A fragments: 4 row-tiles x 4 K-chunks (64 VGPRs)
  short8 a[4][4];
  #pragma unroll
  for (int t = 0; t < 4; t++) {
    const short* ap = zs + (size_t)(rowBase + t * 16 + l15) * DD + quad * 8;
    #pragma unroll
    for (int c = 0; c < 4; c++) a[t][c] = *(const short8*)(ap + c * 32);
  }
  // keep A resident (R10 pathology guard)
  asm volatile("" : "+v"(a[0][0]), "+v"(a[0][1]), "+v"(a[0][2]), "+v"(a[0][3]),
                    "+v"(a[1][0]), "+v"(a[1][1]), "+v"(a[1][2]), "+v"(a[1][3]),
                    "+v"(a[2][0]), "+v"(a[2][1]), "+v"(a[2][2]), "+v"(a[2][3]),
                    "+v"(a[3][0]), "+v"(a[3][1]), "+v"(a[3][2]), "+v"(a[3][3]));

  float rs[4][4];
  #pragma unroll
  for (int t = 0; t < 4; t++)
    #pragma unroll
    for (int r = 0; r < 4; r++) rs[t][r] = 0.0f;

  // drain prologue staging (per-wave; covers A-loads too)
  asm volatile("s_waitcnt vmcnt(0)" ::: "memory");
  __builtin_amdgcn_sched_barrier(0);

  #pragma unroll 1
  for (int rd = 0; rd < NCT; rd++) {
    const int cur = rd & 1;
    char* cb = wb + cur * 4096;

    // issue next round's async staging into the spare private buffer
    if (rd + 1 < NCT) {
      const size_t ro = (size_t)(rd + 1) * 4096;   // 16 cols = 4096 B
      char* nb = wb + (cur ^ 1) * 4096;
      gl_lds16(spE + ro,        nb);
      gl_lds16(spO + ro + 1024, nb + 1024);
      gl_lds16(spE + ro + 2048, nb + 2048);
      gl_lds16(spO + ro + 3072, nb + 3072);
    }

    // one col-tile: 4 swizzled ds_read_b128 + 16 MFMA + 16 exp
    short8 b[4];
    #pragma unroll
    for (int c = 0; c < 4; c++) {
      const int off = l15 * 256 + ((((c * 4 + quad)) ^ (l15 & 7)) << 4);
      b[c] = *(const short8*)(cb + off);
    }
    #pragma unroll
    for (int t = 0; t < 4; t++) {
      float4v acc = {0.f, 0.f, 0.f, 0.f};
      acc = __builtin_amdgcn_mfma_f32_16x16x32_bf16(a[t][0], b[0], acc, 0, 0, 0);
      acc = __builtin_amdgcn_mfma_f32_16x16x32_bf16(a[t][1], b[1], acc, 0, 0, 0);
      acc = __builtin_amdgcn_mfma_f32_16x16x32_bf16(a[t][2], b[2], acc, 0, 0, 0);
      acc = __builtin_amdgcn_mfma_f32_16x16x32_bf16(a[t][3], b[3], acc, 0, 0, 0);
      // C/D: col = l15, row = quad*4 + r [m89/m91]; acc = 2log2e*sim.
      #pragma unroll
      for (int r = 0; r < 4; r++) rs[t][r] += EXP2F(acc[r]);
    }

    // drain this wave's prefetch before next round reads that buffer.
    // "memory" clobber orders the following ds_reads; sched_barrier
    // stops any hoisting across the wait (rule #18).
    asm volatile("s_waitcnt vmcnt(0)" ::: "memory");
    __builtin_amdgcn_sched_barrier(0);
  }

  // row-sums: reduce across the 16 lanes sharing each row, one atomic each
  #pragma unroll
  for (int t = 0; t < 4; t++) {
    #pragma unroll
    for (int r = 0; r < 4; r++) {
      float s = rs[t][r];
      s += __shfl_xor(s, 1);
      s += __shfl_xor(s, 2);
      s += __shfl_xor(s, 4);
      s += __shfl_xor(s, 8);
      if (l15 == 0)
        atomicAdd(&rowsum[rowBase + t * 16 + quad * 4 + r], s);
    }
  }
}

// ---------------- Kernel 3: finalize --------------------------------------
__global__ __launch_bounds__(1024) void ntx_finalize_kernel(
    const float* __restrict__ rowsum, const float* __restrict__ pos,
    float* __restrict__ out) {
  float s = 0.f;
  for (int i = threadIdx.x; i < N2; i += 1024)
    s += __logf(rowsum[i]) - 2.0f * pos[i];
  #pragma unroll
  for (int o = 32; o > 0; o >>= 1) s += __shfl_xor(s, o);
  __shared__ float sm[16];
  const int wave = threadIdx.x >> 6;
  const int lane = threadIdx.x & 63;
  if (lane == 0) sm[wave] = s;
  __syncthreads();
  if (threadIdx.x == 0) {
    float t = 0.f;
    #pragma unroll
    for (int i = 0; i < 16; i++) t += sm[i];
    out[0] = t / (float)N2;
  }
}

extern "C" void kernel_launch(void* const* d_in, const int* in_sizes, int n_in,
                              void* d_out, int out_size, void* d_ws, size_t ws_size,
                              hipStream_t stream) {
  const float* zi = (const float*)d_in[0];
  const float* zj = (const float*)d_in[1];
  float* out = (float*)d_out;

  char* ws = (char*)d_ws;
  bf16* zn = (bf16*)ws;                                   // 8192*128*2 = 2 MB
  float* rowsum = (float*)(ws + (size_t)N2 * DD * 2);     // 32 KB
  float* pos = rowsum + N2;                               // 32 KB

  ntx_norm_kernel<<<BB / 4, 256, 0, stream>>>(zi, zj, zn, rowsum, pos);
  dim3 grid(CSPLIT, N2 / 256);
  ntx_sim_kernel<<<grid, 256, 0, stream>>>(zn, rowsum);
  ntx_finalize_kernel<<<1, 1024, 0, stream>>>(rowsum, pos, out);
}